// Round 7
// baseline (932.161 us; speedup 1.0000x reference)
//
#include <hip/hip_runtime.h>
#include <hip/hip_bf16.h>

#define BB 64
#define PP 192
#define SS 36
#define PI_F 3.14159265358979323846f

typedef __attribute__((ext_vector_type(8))) __bf16 bf16x8;
typedef __attribute__((ext_vector_type(4))) float f32x4;
typedef __attribute__((ext_vector_type(16))) float f32x16;
typedef __attribute__((ext_vector_type(8))) unsigned short us8;

__device__ inline unsigned short f2bf(float f) {
  unsigned int u = __builtin_bit_cast(unsigned int, f);
  unsigned int r = (u + 0x7FFFu + ((u >> 16) & 1u)) >> 16;
  return (unsigned short)r;
}

__device__ inline float bf2f(unsigned short u) {
  return __builtin_bit_cast(float, (unsigned int)u << 16);
}

__device__ inline bf16x8 ld8(const unsigned short* p) {
  us8 v = *(const us8*)p;
  return __builtin_bit_cast(bf16x8, v);
}

// ---------------------------------------------------------------------------
// K0: broadcast priors (P,78) -> (B,P,78)
// ---------------------------------------------------------------------------
__global__ __launch_bounds__(256)
void k_init_priors(const float* __restrict__ priors, float* __restrict__ out) {
  int idx = blockIdx.x * 256 + threadIdx.x;
  if (idx < BB * PP * 78) out[idx] = priors[idx % (PP * 78)];
}

// ---------------------------------------------------------------------------
// K0b: fmap [B][C][H][W] fp32 -> fmT [B][H*W][C] bf16 (pixel-major).
// ---------------------------------------------------------------------------
__global__ __launch_bounds__(256)
void k_transpose(const float* __restrict__ fmap, int HW, int tiles_per_b,
                 unsigned short* __restrict__ fmT) {
  __shared__ unsigned short Ls[64][66];
  int b = blockIdx.x / tiles_per_b;
  int p0 = (blockIdx.x % tiles_per_b) * 64;
  int tid = threadIdx.x;
  for (int idx = tid; idx < 4096; idx += 256) {
    int c = idx >> 6, pos = idx & 63;
    Ls[c][pos] = f2bf(fmap[((size_t)b * 64 + c) * HW + p0 + pos]);
  }
  __syncthreads();
  for (int idx = tid; idx < 4096; idx += 256) {
    int pos = idx >> 6, c = idx & 63;
    fmT[((size_t)b * HW + p0 + pos) * 64 + c] = Ls[c][pos];
  }
}

// ---------------------------------------------------------------------------
// Repack weights to bf16 MFMA-A layouts (same as round 6).
// ---------------------------------------------------------------------------
__global__ __launch_bounds__(256)
void k_repack(const float* __restrict__ cw,
              const float* __restrict__ c0, const float* __restrict__ c1,
              const float* __restrict__ c2, const float* __restrict__ fcw,
              const float* __restrict__ clsW, const float* __restrict__ regW,
              const float* __restrict__ chw, const float* __restrict__ rhw,
              unsigned short* __restrict__ Wr, unsigned short* __restrict__ Wc,
              unsigned short* __restrict__ fw, unsigned short* __restrict__ wm) {
  int idx = blockIdx.x * 256 + threadIdx.x;
  if (idx < 82944) {
    int c = idx & 63; int t = idx >> 6; int o = t % 48; t /= 48;
    int k = t % 9; int s = t / 9;
    Wr[idx] = f2bf(cw[((size_t)(s * 48 + o) * 64 + c) * 9 + k]);
  } else if (idx < 82944 + 165888) {
    int r = idx - 82944;
    int st, base, NC;
    if (r < 27648)            { st = 0; base = 0;     NC = 1; }
    else if (r < 82944)       { st = 1; base = 27648; NC = 2; }
    else                      { st = 2; base = 82944; NC = 3; }
    int r2 = r - base;
    int slice_id = r2 >> 10;
    int m = (r2 >> 9) & 1;
    int lane = (r2 >> 3) & 63;
    int j = r2 & 7;
    int i = slice_id / 27;
    int rem = slice_id % 27;
    int t = rem / 3;
    int s = rem % 3;
    int o = m * 32 + (lane & 31);
    int c = s * 16 + (lane >> 5) * 8 + j;
    const float* src = (st == 0) ? c0 : (st == 1) ? c1 : c2;
    Wc[r] = f2bf(src[((size_t)o * (NC * 48) + i * 48 + c) * 9 + t]);
  } else if (idx < 82944 + 165888 + 147456) {
    int q = idx - (82944 + 165888);
    int h = q / 2304; int kp = q % 2304; int j = kp >> 6; int c = kp & 63;
    fw[q] = f2bf(fcw[(size_t)h * 2304 + c * 36 + j]);
  } else if (idx < 82944 + 165888 + 147456 + 22528) {
    int q = idx - (82944 + 165888 + 147456);
    unsigned short v;
    if (q < 4096)        v = f2bf(clsW[q]);
    else if (q < 8192)   v = f2bf(clsW[4096 + (q - 4096)]);
    else if (q < 12288)  v = f2bf(regW[q - 8192]);
    else if (q < 16384)  v = f2bf(regW[4096 + (q - 12288)]);
    else if (q < 17408) { int r = q - 16384; int o = r >> 6, c = r & 63;
                          v = (o < 2) ? f2bf(chw[o * 64 + c]) : (unsigned short)0; }
    else                { int r = q - 17408; int o = r >> 6, c = r & 63;
                          v = (o < 76) ? f2bf(rhw[o * 64 + c]) : (unsigned short)0; }
    wm[q] = v;
  }
}

// ---------------------------------------------------------------------------
// K2: key/value in MFMA-B layouts. Block = (b, 64-key tile); 256 blocks.
// ---------------------------------------------------------------------------
__global__ __launch_bounds__(256)
void k_kv(const unsigned short* __restrict__ fmT, int H, int W,
          const float* __restrict__ fkey_w, const float* __restrict__ fkey_scale,
          const float* __restrict__ fkey_shift,
          const float* __restrict__ fval_w, const float* __restrict__ fval_b,
          unsigned short* __restrict__ keyT, unsigned short* __restrict__ valB) {
  __shared__ float pix[64][68];
  __shared__ __align__(16) unsigned short kout[64][80];
  __shared__ __align__(16) unsigned short vout[64][80];
  int tid = threadIdx.x;
  int b = blockIdx.x >> 2;
  int k0 = (blockIdx.x & 3) * 64;

  {
    int key = tid >> 2, cq = tid & 3;
    int k = k0 + key;
    float v[16];
    if (k < 250) {
      int r = k / 25, c2 = k % 25;
      int iy = (r * H) / 10, ix = (c2 * W) / 25;
      const unsigned short* src = fmT + ((size_t)b * H * W + iy * W + ix) * 64 + cq * 16;
      us8 a = *(const us8*)src;
      us8 bb = *(const us8*)(src + 8);
#pragma unroll
      for (int e = 0; e < 8; ++e) { v[e] = bf2f(a[e]); v[8 + e] = bf2f(bb[e]); }
    } else {
#pragma unroll
      for (int e = 0; e < 16; ++e) v[e] = 0.f;
    }
#pragma unroll
    for (int e = 0; e < 16; ++e) pix[key][cq * 16 + e] = v[e];
  }
  __syncthreads();

  {
    int o = tid >> 2, kq = tid & 3;
    float ak[16], av[16];
#pragma unroll
    for (int kk = 0; kk < 16; ++kk) { ak[kk] = 0.f; av[kk] = 0.f; }
    for (int c = 0; c < 64; ++c) {
      float wk = fkey_w[o * 64 + c], wvv = fval_w[o * 64 + c];
#pragma unroll
      for (int kk = 0; kk < 16; ++kk) {
        float pv = pix[kq * 16 + kk][c];
        ak[kk] += pv * wk; av[kk] += pv * wvv;
      }
    }
    float sc_ = fkey_scale[o], sh = fkey_shift[o], vb_ = fval_b[o];
#pragma unroll
    for (int kk = 0; kk < 16; ++kk) {
      int k = kq * 16 + kk;
      float kf = ak[kk] * sc_ + sh; kf = kf > 0.f ? kf : 0.f;
      kout[k][o] = f2bf(kf);
      vout[o][k] = f2bf(av[kk] + vb_);
    }
  }
  __syncthreads();

  {
    int row = tid >> 2, oq = tid & 3;
    *(us8*)(keyT + ((size_t)b * 256 + k0 + row) * 64 + oq * 16)     = *(us8*)&kout[row][oq * 16];
    *(us8*)(keyT + ((size_t)b * 256 + k0 + row) * 64 + oq * 16 + 8) = *(us8*)&kout[row][oq * 16 + 8];
    *(us8*)(valB + ((size_t)b * 64 + row) * 256 + k0 + oq * 16)     = *(us8*)&vout[row][oq * 16];
    *(us8*)(valB + ((size_t)b * 64 + row) * 256 + k0 + oq * 16 + 8) = *(us8*)&vout[row][oq * 16 + 8];
  }
}

// ---------------------------------------------------------------------------
// K1a: fused gather + conv_s, WAVE-PRIVATE (no __syncthreads). Each wave owns
// 2 rois = 96 rows (4 guard + 88 + 4 guard) in its own LDS region; tap
// overhang rows (96..103) read the next region's zero front-guard or
// predicated-off columns. 1536 blocks x 256.
// ---------------------------------------------------------------------------
template <int STAGE>
__global__ __launch_bounds__(256, 3)
void k_gatherconv(const unsigned short* __restrict__ fmT,
                  const float* __restrict__ priors_cur,
                  const unsigned short* __restrict__ Wr,
                  const float* __restrict__ cscale, const float* __restrict__ cshift,
                  unsigned short* __restrict__ cfg) {
  constexpr int H = (STAGE == 0) ? 64 : (STAGE == 1) ? 32 : 16;
  constexpr int W = (STAGE == 0) ? 80 : (STAGE == 1) ? 40 : 20;
  constexpr int HW = H * W;

  __shared__ __align__(16) unsigned short Xs[392][64];   // 4 x 96 + 8 tail
  __shared__ float posx[4][2][36], posy[4][2][36];

  int tid = threadIdx.x;
  int wv = tid >> 6, lane = tid & 63;
  int l15 = lane & 15, quad = lane >> 4;
  int r0 = blockIdx.x * 8 + wv * 2;            // this wave's first roi
  unsigned short* my = &Xs[wv * 96][0];

  // positions for this wave's 2 rois (wave-internal ordering only)
  for (int it = lane; it < 72; it += 64) {
    int q = it / 36, j = it % 36;
    int k = 35 - j;
    int sx = (int)(((float)k / 35.0f) * 71.0f);
    float px = priors_cur[(size_t)(r0 + q) * 78 + 6 + sx];
    posx[wv][q][j] = px * (float)(W - 1);
    posy[wv][q][j] = (1.0f - (float)sx / 71.0f) * (float)(H - 1);
  }

  // gather: 96 rows x 8 chunks = 768 items, 12 per lane
  for (int it = lane; it < 768; it += 64) {
    int row = it >> 3, ch8 = it & 7;
    int p = row - 4;
    unsigned short pk[8] = {0, 0, 0, 0, 0, 0, 0, 0};
    if (p >= 0 && p < 88) {
      int q = p / 44, x = p % 44;
      if (x >= 4 && x < 40) {
        int j = x - 4;
        int b = (r0 + q) / PP;
        float fx = posx[wv][q][j];
        float fy = posy[wv][q][j];
        float x0 = floorf(fx), y0 = floorf(fy);
        float wx = fx - x0, wy = fy - y0;
        float xs2[2] = {x0, x0 + 1.f};
        float ys2[2] = {y0, y0 + 1.f};
        float wxs[2] = {1.f - wx, wx};
        float wys[2] = {1.f - wy, wy};
        float accf[8] = {0.f, 0.f, 0.f, 0.f, 0.f, 0.f, 0.f, 0.f};
#pragma unroll
        for (int ty = 0; ty < 2; ++ty)
#pragma unroll
          for (int tx = 0; tx < 2; ++tx) {
            float xf = xs2[tx], yf = ys2[ty];
            bool v = (xf >= 0.f) && (xf <= (float)(W - 1)) &&
                     (yf >= 0.f) && (yf <= (float)(H - 1));
            int xi = (int)fminf(fmaxf(xf, 0.f), (float)(W - 1));
            int yi = (int)fminf(fmaxf(yf, 0.f), (float)(H - 1));
            float wgt = v ? (wxs[tx] * wys[ty]) : 0.f;
            const us8 vv = *(const us8*)(fmT + ((size_t)b * HW + yi * W + xi) * 64 + ch8 * 8);
#pragma unroll
            for (int e = 0; e < 8; ++e) accf[e] += wgt * bf2f(vv[e]);
          }
#pragma unroll
        for (int e = 0; e < 8; ++e) pk[e] = f2bf(accf[e]);
      }
    }
    *(us8*)&my[row * 64 + (((ch8 ^ (row & 7))) * 8)] = *(us8*)pk;
  }

  // conv MFMA: 3 m-tiles (48 out) x 6 n-tiles (96 positions), 16x16x32
  f32x4 acc[3][6];
#pragma unroll
  for (int m = 0; m < 3; ++m)
#pragma unroll
    for (int n = 0; n < 6; ++n) acc[m][n] = (f32x4)0.f;

#pragma unroll
  for (int k = 0; k < 9; ++k) {
#pragma unroll
    for (int kk = 0; kk < 2; ++kk) {
      bf16x8 af[3];
#pragma unroll
      for (int m = 0; m < 3; ++m)
        af[m] = ld8(Wr + ((size_t)(k * 48 + m * 16 + l15)) * 64 + kk * 32 + quad * 8);
#pragma unroll
      for (int n = 0; n < 6; ++n) {
        int row = n * 16 + l15 + k;              // up to 103 (tail rows)
        int pc = (kk * 4 + quad) ^ (row & 7);
        bf16x8 bfr = ld8(&my[row * 64 + pc * 8]);
#pragma unroll
        for (int m = 0; m < 3; ++m)
          acc[m][n] = __builtin_amdgcn_mfma_f32_16x16x32_bf16(af[m], bfr, acc[m][n], 0, 0, 0);
      }
    }
  }

#pragma unroll
  for (int n = 0; n < 6; ++n) {
    int p = n * 16 + l15;
    if (p < 88) {
      int q = p / 44, x = p % 44;
      if (x >= 4 && x < 40) {
        int bp = r0 + q;
#pragma unroll
        for (int m = 0; m < 3; ++m) {
          int o0 = m * 16 + quad * 4;
          unsigned short pk[4];
#pragma unroll
          for (int rg = 0; rg < 4; ++rg) {
            float v = acc[m][n][rg] * cscale[o0 + rg] + cshift[o0 + rg];
            pk[rg] = f2bf(v > 0.f ? v : 0.f);
          }
          *(uint2*)(cfg + ((size_t)bp * 36 + (x - 4)) * 48 + o0) = *(uint2*)pk;
        }
      }
    }
  }
}

// ---------------------------------------------------------------------------
// K1b: cat conv, WAVE-PRIVATE 32x32x16 MFMA (no __syncthreads). Each wave:
// 2 rois = 96 rows = exactly 3 n-tiles of 32. Stages its own B per NC-group.
// ---------------------------------------------------------------------------
template <int STAGE>
__global__ __launch_bounds__(256, 3)
void k_cat(const unsigned short* __restrict__ cfg_all,
           const unsigned short* __restrict__ Wc,
           const float* __restrict__ kscale, const float* __restrict__ kshift,
           unsigned short* __restrict__ catf) {
  constexpr int NC = STAGE + 1;
  __shared__ __align__(16) unsigned short cfs[392][64];  // 4 x 96 + 8 tail
  int tid = threadIdx.x;
  int wv = tid >> 6, lane = tid & 63;
  int l31 = lane & 31, half = lane >> 5;
  int r0 = blockIdx.x * 8 + wv * 2;
  unsigned short* my = &cfs[wv * 96][0];

  // zero upper chunks (logical ch 48..63) once; they stay zero across groups
  for (int it = lane; it < 192; it += 64) {
    int row = it >> 1, ch = 6 + (it & 1);
    *(us8*)&my[row * 64 + ((ch ^ (row & 7)) * 8)] = (us8)(unsigned short)0;
  }

  f32x16 acc[2][3];
#pragma unroll
  for (int m = 0; m < 2; ++m)
#pragma unroll
    for (int n = 0; n < 3; ++n) acc[m][n] = (f32x16)0.f;

#pragma unroll
  for (int i = 0; i < NC; ++i) {
    // stage this wave's 96 rows x 6 chunks (9 items/lane), wave-internal order
    for (int it = lane; it < 576; it += 64) {
      int row = it / 6, ch = it % 6;
      int p = row - 4;
      us8 v = (us8)(unsigned short)0;
      if (p >= 0 && p < 88) {
        int q = p / 44, x = p % 44;
        if (x >= 4 && x < 40) {
          v = *(const us8*)(cfg_all + (size_t)i * (12288ull * 36 * 48) +
                            ((size_t)(r0 + q) * 36 + (x - 4)) * 48 + ch * 8);
        }
      }
      *(us8*)&my[row * 64 + ((ch ^ (row & 7)) * 8)] = v;
    }

#pragma unroll
    for (int t = 0; t < 9; ++t) {
#pragma unroll
      for (int s = 0; s < 3; ++s) {
        int slice_id = i * 27 + t * 3 + s;
        bf16x8 a0 = ld8(Wc + (size_t)(slice_id * 2 + 0) * 512 + lane * 8);
        bf16x8 a1 = ld8(Wc + (size_t)(slice_id * 2 + 1) * 512 + lane * 8);
#pragma unroll
        for (int n = 0; n < 3; ++n) {
          int row = n * 32 + l31 + t;            // up to 103 (tail rows)
          int q = (s * 2 + half) ^ (row & 7);
          bf16x8 b = ld8(&my[row * 64 + q * 8]);
          acc[0][n] = __builtin_amdgcn_mfma_f32_32x32x16_bf16(a0, b, acc[0][n], 0, 0, 0);
          acc[1][n] = __builtin_amdgcn_mfma_f32_32x32x16_bf16(a1, b, acc[1][n], 0, 0, 0);
        }
      }
    }
  }

#pragma unroll
  for (int n = 0; n < 3; ++n) {
    int p = n * 32 + l31;
    if (p < 88) {
      int q = p / 44, x = p % 44;
      if (x >= 4 && x < 40) {
        int bp = r0 + q;
        unsigned short* dst = catf + ((size_t)bp * 36 + (x - 4)) * 64;
#pragma unroll
        for (int m = 0; m < 2; ++m) {
#pragma unroll
          for (int r = 0; r < 4; ++r) {
            int o0 = m * 32 + r * 8 + half * 4;
            unsigned short pk[4];
#pragma unroll
            for (int g = 0; g < 4; ++g) {
              int o = o0 + g;
              float v = acc[m][n][r * 4 + g] * kscale[o] + kshift[o];
              pk[g] = f2bf(v > 0.f ? v : 0.f);
            }
            *(uint2*)(dst + o0) = *(uint2*)pk;
          }
        }
      }
    }
  }
}

// ---------------------------------------------------------------------------
// helper: one 16(M)x16(N)x64(K) GEMM tile.
// ---------------------------------------------------------------------------
__device__ inline f32x4 gemm_tile(const unsigned short* __restrict__ Wrow0,
                                  const unsigned short* Xl, int l15, int quad) {
  f32x4 a = (f32x4)0.f;
#pragma unroll
  for (int kk = 0; kk < 2; ++kk) {
    bf16x8 af = ld8(Wrow0 + (size_t)l15 * 64 + kk * 32 + quad * 8);
    bf16x8 bx = ld8(Xl + l15 * 64 + (((kk * 4 + quad) ^ (l15 & 7)) * 8));
    a = __builtin_amdgcn_mfma_f32_16x16x32_bf16(af, bx, a, 0, 0, 0);
  }
  return a;
}

// ---------------------------------------------------------------------------
// K3: FUSED fc-GEMM + LayerNorm + attention + MLP heads + tan epilogue.
// One wave per 16 rois; grid = 768. rf passes through LDS (no roi_fc buffer).
// ---------------------------------------------------------------------------
__global__ __launch_bounds__(64)
void k_fc_att(const unsigned short* __restrict__ catf,
              const unsigned short* __restrict__ fw,
              const float* __restrict__ fc_b,
              const float* __restrict__ ln_g, const float* __restrict__ ln_b,
              const unsigned short* __restrict__ keyT,
              const unsigned short* __restrict__ valB,
              const float* __restrict__ fq_w, const float* __restrict__ fq_b,
              const float* __restrict__ attW_w, const float* __restrict__ attW_b,
              const unsigned short* __restrict__ wm,
              const float* __restrict__ cls_mlp_b, const float* __restrict__ reg_mlp_b,
              const float* __restrict__ cls_head_b, const float* __restrict__ reg_head_b,
              const float* __restrict__ priors_cur,
              float* __restrict__ priors_next,
              float* __restrict__ preds) {
  __shared__ __align__(16) unsigned char smem[2048 + 4608 + 8192];
  unsigned short* qx = (unsigned short*)smem;            // q / x union [16][64]
  unsigned char* Bb = smem + 2048;                       // rf / hA,hB union
  unsigned char* Cb = smem + 2048 + 4608;                // fcb / sim / rego union

  int lane = threadIdx.x;
  int l15 = lane & 15, quad = lane >> 4;
  int rb = blockIdx.x * 16;
  int b = rb / PP;
  int p_base = rb % PP;

  float* rf = (float*)Bb;                                // [16][68] f32
  unsigned short* hA = (unsigned short*)Bb;              // [16][64] bf16
  unsigned short* hB = (unsigned short*)(Bb + 2304);
  float* fcb = (float*)Cb;                               // [16][68] f32 (dies before sim)
  unsigned short* simw = (unsigned short*)Cb;            // [16][256] bf16
  unsigned short* rego = (unsigned short*)Cb;            // [16][80] bf16
  unsigned short* clso = (unsigned short*)(Cb + 2560);   // [16][2]

  // ---- phase 0: fc GEMM (M=64 hidden, N=16 rois, K=2304) ----
  {
    f32x4 acc[4];
#pragma unroll
    for (int m = 0; m < 4; ++m) acc[m] = (f32x4)0.f;
    for (int ks = 0; ks < 72; ++ks) {
      int j = ks >> 1, ch = (ks & 1) * 32;
      bf16x8 bfr = ld8(catf + ((size_t)(rb + l15) * 36 + j) * 64 + ch + quad * 8);
#pragma unroll
      for (int m = 0; m < 4; ++m) {
        bf16x8 af = ld8(fw + (size_t)(m * 16 + l15) * 2304 + ks * 32 + quad * 8);
        acc[m] = __builtin_amdgcn_mfma_f32_16x16x32_bf16(af, bfr, acc[m], 0, 0, 0);
      }
    }
#pragma unroll
    for (int m = 0; m < 4; ++m) {
      f32x4 v;
#pragma unroll
      for (int rg = 0; rg < 4; ++rg) v[rg] = acc[m][rg] + fc_b[m * 16 + quad * 4 + rg];
      *(f32x4*)&fcb[l15 * 68 + m * 16 + quad * 4] = v;
    }
  }

  // ---- phase 1: LayerNorm + relu -> rf (f32) + q (bf16, swizzled) ----
  for (int rr = 0; rr < 16; ++rr) {
    float y = fcb[rr * 68 + lane];
    float s = y;
#pragma unroll
    for (int off = 32; off > 0; off >>= 1) s += __shfl_xor(s, off, 64);
    float mu = s * (1.f / 64.f);
    float d = y - mu;
    float v2 = d * d;
#pragma unroll
    for (int off = 32; off > 0; off >>= 1) v2 += __shfl_xor(v2, off, 64);
    float var = v2 * (1.f / 64.f);
    float r = d / sqrtf(var + 1e-5f) * ln_g[lane] + ln_b[lane];
    r = r > 0.f ? r : 0.f;
    rf[rr * 68 + lane] = r;
    int p = p_base + rr;
    float q = r * fq_w[p] + fq_b[p];
    q = q > 0.f ? q : 0.f;
    qx[rr * 64 + (((lane >> 3) ^ (rr & 7)) * 8) + (lane & 7)] = f2bf(q);
  }

  // ---- phase 2: QK^T + in-register softmax ----
  f32x4 sc[16];
#pragma unroll
  for (int nt = 0; nt < 16; ++nt) sc[nt] = (f32x4)0.f;
  const unsigned short* kb = keyT + (size_t)b * 256 * 64;
#pragma unroll
  for (int kk = 0; kk < 2; ++kk) {
    bf16x8 af = ld8(&qx[l15 * 64 + (((kk * 4 + quad) ^ (l15 & 7)) * 8)]);
#pragma unroll
    for (int nt = 0; nt < 16; ++nt) {
      bf16x8 bf_ = ld8(kb + (size_t)(nt * 16 + l15) * 64 + kk * 32 + quad * 8);
      sc[nt] = __builtin_amdgcn_mfma_f32_16x16x32_bf16(af, bf_, sc[nt], 0, 0, 0);
    }
  }
  float mx[4] = {-1e30f, -1e30f, -1e30f, -1e30f};
#pragma unroll
  for (int nt = 0; nt < 16; ++nt)
#pragma unroll
    for (int rg = 0; rg < 4; ++rg) {
      float s = sc[nt][rg] * 0.125f;
      if (nt == 15 && l15 >= 10) s = -1e30f;
      sc[nt][rg] = s;
      mx[rg] = fmaxf(mx[rg], s);
    }
#pragma unroll
  for (int rg = 0; rg < 4; ++rg)
#pragma unroll
    for (int off = 1; off < 16; off <<= 1)
      mx[rg] = fmaxf(mx[rg], __shfl_xor(mx[rg], off, 64));
  float sm[4] = {0.f, 0.f, 0.f, 0.f};
#pragma unroll
  for (int nt = 0; nt < 16; ++nt)
#pragma unroll
    for (int rg = 0; rg < 4; ++rg) {
      float e = expf(sc[nt][rg] - mx[rg]);
      sc[nt][rg] = e;
      sm[rg] += e;
    }
#pragma unroll
  for (int rg = 0; rg < 4; ++rg)
#pragma unroll
    for (int off = 1; off < 16; off <<= 1)
      sm[rg] += __shfl_xor(sm[rg], off, 64);
  float rs[4];
#pragma unroll
  for (int rg = 0; rg < 4; ++rg) rs[rg] = 1.f / sm[rg];
#pragma unroll
  for (int nt = 0; nt < 16; ++nt)
#pragma unroll
    for (int rg = 0; rg < 4; ++rg) {
      int row = quad * 4 + rg, col = nt * 16 + l15;
      simw[row * 256 + (((col >> 3) ^ (row & 7)) * 8) + (col & 7)] = f2bf(sc[nt][rg] * rs[rg]);
    }

  // ---- phase 3: PV + residual + attW ----
  f32x4 cv[4];
#pragma unroll
  for (int nt = 0; nt < 4; ++nt) cv[nt] = (f32x4)0.f;
  const unsigned short* vb = valB + (size_t)b * 64 * 256;
#pragma unroll
  for (int ks = 0; ks < 8; ++ks) {
    bf16x8 af = ld8(&simw[l15 * 256 + (((ks * 4 + quad) ^ (l15 & 7)) * 8)]);
#pragma unroll
    for (int nt = 0; nt < 4; ++nt) {
      bf16x8 bf_ = ld8(vb + (size_t)(nt * 16 + l15) * 256 + ks * 32 + quad * 8);
      cv[nt] = __builtin_amdgcn_mfma_f32_16x16x32_bf16(af, bf_, cv[nt], 0, 0, 0);
    }
  }
#pragma unroll
  for (int rg = 0; rg < 4; ++rg) {
    int row = quad * 4 + rg;
    int p = p_base + row;
    float aw = attW_w[p], ab = attW_b[p];
#pragma unroll
    for (int nt = 0; nt < 4; ++nt) {
      int c = nt * 16 + l15;
      float xv = rf[row * 68 + c] + cv[nt][rg] * aw + ab;
      qx[row * 64 + (((c >> 3) ^ (row & 7)) * 8) + (c & 7)] = f2bf(xv);
    }
  }

  // ---- phase 4: MLP chains ----
  const unsigned short* xw = qx;
#pragma unroll
  for (int mt = 0; mt < 4; ++mt) {
    f32x4 a = gemm_tile(wm + 0 + mt * 1024, xw, l15, quad);
#pragma unroll
    for (int rg = 0; rg < 4; ++rg) {
      int o = mt * 16 + quad * 4 + rg;
      float v = a[rg] + cls_mlp_b[o]; v = v > 0.f ? v : 0.f;
      hA[l15 * 64 + (((o >> 3) ^ (l15 & 7)) * 8) + (o & 7)] = f2bf(v);
    }
  }
#pragma unroll
  for (int mt = 0; mt < 4; ++mt) {
    f32x4 a = gemm_tile(wm + 4096 + mt * 1024, hA, l15, quad);
#pragma unroll
    for (int rg = 0; rg < 4; ++rg) {
      int o = mt * 16 + quad * 4 + rg;
      float v = a[rg] + cls_mlp_b[64 + o]; v = v > 0.f ? v : 0.f;
      hB[l15 * 64 + (((o >> 3) ^ (l15 & 7)) * 8) + (o & 7)] = f2bf(v);
    }
  }
  {
    f32x4 a = gemm_tile(wm + 16384, hB, l15, quad);
#pragma unroll
    for (int rg = 0; rg < 4; ++rg) {
      int o = quad * 4 + rg;
      if (o < 2) clso[l15 * 2 + o] = f2bf(a[rg] + cls_head_b[o]);
    }
  }
#pragma unroll
  for (int mt = 0; mt < 4; ++mt) {
    f32x4 a = gemm_tile(wm + 8192 + mt * 1024, xw, l15, quad);
#pragma unroll
    for (int rg = 0; rg < 4; ++rg) {
      int o = mt * 16 + quad * 4 + rg;
      float v = a[rg] + reg_mlp_b[o]; v = v > 0.f ? v : 0.f;
      hA[l15 * 64 + (((o >> 3) ^ (l15 & 7)) * 8) + (o & 7)] = f2bf(v);
    }
  }
#pragma unroll
  for (int mt = 0; mt < 4; ++mt) {
    f32x4 a = gemm_tile(wm + 12288 + mt * 1024, hA, l15, quad);
#pragma unroll
    for (int rg = 0; rg < 4; ++rg) {
      int o = mt * 16 + quad * 4 + rg;
      float v = a[rg] + reg_mlp_b[64 + o]; v = v > 0.f ? v : 0.f;
      hB[l15 * 64 + (((o >> 3) ^ (l15 & 7)) * 8) + (o & 7)] = f2bf(v);
    }
  }
#pragma unroll
  for (int mt = 0; mt < 5; ++mt) {
    f32x4 a = gemm_tile(wm + 17408 + mt * 1024, hB, l15, quad);
#pragma unroll
    for (int rg = 0; rg < 4; ++rg) {
      int o = mt * 16 + quad * 4 + rg;
      if (o < 76) rego[l15 * 80 + o] = f2bf(a[rg] + reg_head_b[o]);
    }
  }

  // ---- phase 5: epilogue (4 lanes per roi) ----
  {
    int p_local = lane >> 2, g = lane & 3;
    int bp = rb + p_local;
    const float* pc = priors_cur + (size_t)bp * 78;
    float r0v = bf2f(rego[p_local * 80 + 0]);
    float r1v = bf2f(rego[p_local * 80 + 1]);
    float r2v = bf2f(rego[p_local * 80 + 2]);
    float r3v = bf2f(rego[p_local * 80 + 3]);
    float p0 = pc[2] + r0v;
    float p1 = pc[3] + r1v;
    float p2 = pc[4] + r2v;
    float* po = preds + (size_t)bp * 78;
    float* pn = priors_next ? priors_next + (size_t)bp * 78 : nullptr;
    if (g == 0) {
      float c0v = bf2f(clso[p_local * 2 + 0]);
      float c1v = bf2f(clso[p_local * 2 + 1]);
      po[0] = c0v; po[1] = c1v;
      po[2] = p0; po[3] = p1; po[4] = p2; po[5] = r3v;
      if (pn) { pn[0] = c0v; pn[1] = c1v; pn[2] = p0; pn[3] = p1; pn[4] = p2; pn[5] = r3v; }
    }
    float t = tanf(p2 * PI_F + 1e-5f);
    float inv_t = 512.f / t;
#pragma unroll 2
    for (int i = g * 18; i < g * 18 + 18; ++i) {
      float py = 1.0f - (float)i / 71.0f;
      float offs = (p1 * 639.0f + (1.0f - py - p0) * inv_t) * (1.0f / 639.0f);
      po[6 + i] = offs + bf2f(rego[p_local * 80 + 4 + i]);
      if (pn) pn[6 + i] = offs;
    }
  }
}

// ---------------------------------------------------------------------------
extern "C" void kernel_launch(void* const* d_in, const int* in_sizes, int n_in,
                              void* d_out, int out_size, void* d_ws, size_t ws_size,
                              hipStream_t stream) {
  (void)in_sizes; (void)n_in; (void)out_size; (void)ws_size;
  const float* feat[3] = {(const float*)d_in[0], (const float*)d_in[1], (const float*)d_in[2]};
  const float* priors      = (const float*)d_in[3];
  const float* convs_w     = (const float*)d_in[4];
  const float* convs_scale = (const float*)d_in[5];
  const float* convs_shift = (const float*)d_in[6];
  const float* cat_w[3]    = {(const float*)d_in[7], (const float*)d_in[8], (const float*)d_in[9]};
  const float* cat_scale   = (const float*)d_in[10];
  const float* cat_shift   = (const float*)d_in[11];
  const float* fkey_w      = (const float*)d_in[12];
  const float* fkey_scale  = (const float*)d_in[13];
  const float* fkey_shift  = (const float*)d_in[14];
  const float* fval_w      = (const float*)d_in[15];
  const float* fval_b      = (const float*)d_in[16];
  const float* fq_w        = (const float*)d_in[17];
  const float* fq_b        = (const float*)d_in[18];
  const float* attW_w      = (const float*)d_in[19];
  const float* attW_b      = (const float*)d_in[20];
  const float* fc_w        = (const float*)d_in[21];
  const float* fc_b        = (const float*)d_in[22];
  const float* ln_g        = (const float*)d_in[23];
  const float* ln_b        = (const float*)d_in[24];
  const float* cls_mlp_w   = (const float*)d_in[25];
  const float* cls_mlp_b   = (const float*)d_in[26];
  const float* reg_mlp_w   = (const float*)d_in[27];
  const float* reg_mlp_b   = (const float*)d_in[28];
  const float* cls_head_w  = (const float*)d_in[29];
  const float* cls_head_b  = (const float*)d_in[30];
  const float* reg_head_w  = (const float*)d_in[31];
  const float* reg_head_b  = (const float*)d_in[32];
  float* out = (float*)d_out;

  char* wp = (char*)d_ws;
  auto alloc = [&](size_t bytes) { char* r = wp; wp += (bytes + 255) & ~(size_t)255; return r; };

  float* priA   = (float*)alloc((size_t)BB * PP * 78 * 4);
  float* priB   = (float*)alloc((size_t)BB * PP * 78 * 4);
  unsigned short* keyT = (unsigned short*)alloc((size_t)BB * 256 * 64 * 2);
  unsigned short* valB = (unsigned short*)alloc((size_t)BB * 64 * 256 * 2);
  unsigned short* Wr   = (unsigned short*)alloc(82944ull * 2);
  unsigned short* Wc   = (unsigned short*)alloc(165888ull * 2);
  unsigned short* fw   = (unsigned short*)alloc(147456ull * 2);
  unsigned short* wm   = (unsigned short*)alloc(22528ull * 2);
  unsigned short* cfg  = (unsigned short*)alloc(3ull * 12288 * 36 * 48 * 2);
  unsigned short* catf = (unsigned short*)alloc(12288ull * 36 * 64 * 2);
  unsigned short* fmT  = (unsigned short*)alloc((size_t)BB * 64 * 80 * 64 * 2);

  const int HW[3][2] = {{64, 80}, {32, 40}, {16, 20}};
  const size_t wcoff[3] = {0, 27648, 82944};

  k_init_priors<<<dim3((BB * PP * 78 + 255) / 256), dim3(256), 0, stream>>>(priors, priA);
  k_repack<<<dim3((418816 + 255) / 256), dim3(256), 0, stream>>>(
      convs_w, cat_w[0], cat_w[1], cat_w[2], fc_w,
      cls_mlp_w, reg_mlp_w, cls_head_w, reg_head_w, Wr, Wc, fw, wm);

  float* pcur = priA;
  float* pnext = priB;
  for (int s = 0; s < 3; ++s) {
    int H = HW[s][0], W = HW[s][1];
    int hw = H * W;
    int tiles = hw / 64;
    k_transpose<<<dim3(BB * tiles), dim3(256), 0, stream>>>(feat[s], hw, tiles, fmT);

    k_kv<<<dim3(BB * 4), dim3(256), 0, stream>>>(
        fmT, H, W, fkey_w, fkey_scale, fkey_shift, fval_w, fval_b, keyT, valB);

    if (s == 0) {
      k_gatherconv<0><<<dim3(1536), dim3(256), 0, stream>>>(
          fmT, pcur, Wr + 0 * 27648, convs_scale + 0, convs_shift + 0,
          cfg + 0ull * 12288 * 36 * 48);
      k_cat<0><<<dim3(1536), dim3(256), 0, stream>>>(
          cfg, Wc + wcoff[0], cat_scale + 0, cat_shift + 0, catf);
    } else if (s == 1) {
      k_gatherconv<1><<<dim3(1536), dim3(256), 0, stream>>>(
          fmT, pcur, Wr + 1 * 27648, convs_scale + 48, convs_shift + 48,
          cfg + 1ull * 12288 * 36 * 48);
      k_cat<1><<<dim3(1536), dim3(256), 0, stream>>>(
          cfg, Wc + wcoff[1], cat_scale + 64, cat_shift + 64, catf);
    } else {
      k_gatherconv<2><<<dim3(1536), dim3(256), 0, stream>>>(
          fmT, pcur, Wr + 2 * 27648, convs_scale + 96, convs_shift + 96,
          cfg + 2ull * 12288 * 36 * 48);
      k_cat<2><<<dim3(1536), dim3(256), 0, stream>>>(
          cfg, Wc + wcoff[2], cat_scale + 128, cat_shift + 128, catf);
    }

    k_fc_att<<<dim3(768), dim3(64), 0, stream>>>(
        catf, fw, fc_b, ln_g, ln_b, keyT, valB, fq_w, fq_b, attW_w, attW_b, wm,
        cls_mlp_b, reg_mlp_b, cls_head_b, reg_head_b,
        pcur, (s < 2) ? pnext : (float*)nullptr,
        out + (size_t)s * BB * PP * 78);

    float* tmp = pcur; pcur = pnext; pnext = tmp;
  }
}

// Round 8
// 894.488 us; speedup vs baseline: 1.0421x; 1.0421x over previous
//
#include <hip/hip_runtime.h>
#include <hip/hip_bf16.h>

#define BB 64
#define PP 192
#define SS 36
#define PI_F 3.14159265358979323846f

typedef __attribute__((ext_vector_type(8))) __bf16 bf16x8;
typedef __attribute__((ext_vector_type(4))) float f32x4;
typedef __attribute__((ext_vector_type(16))) float f32x16;
typedef __attribute__((ext_vector_type(8))) unsigned short us8;

__device__ inline unsigned short f2bf(float f) {
  unsigned int u = __builtin_bit_cast(unsigned int, f);
  unsigned int r = (u + 0x7FFFu + ((u >> 16) & 1u)) >> 16;
  return (unsigned short)r;
}

__device__ inline float bf2f(unsigned short u) {
  return __builtin_bit_cast(float, (unsigned int)u << 16);
}

__device__ inline bf16x8 ld8(const unsigned short* p) {
  us8 v = *(const us8*)p;
  return __builtin_bit_cast(bf16x8, v);
}

// ---------------------------------------------------------------------------
// K0: broadcast priors (P,78) -> (B,P,78)
// ---------------------------------------------------------------------------
__global__ __launch_bounds__(256)
void k_init_priors(const float* __restrict__ priors, float* __restrict__ out) {
  int idx = blockIdx.x * 256 + threadIdx.x;
  if (idx < BB * PP * 78) out[idx] = priors[idx % (PP * 78)];
}

// ---------------------------------------------------------------------------
// K0b: fmap [B][C][H][W] fp32 -> fmT [B][H*W][C] bf16 (pixel-major).
// ---------------------------------------------------------------------------
__global__ __launch_bounds__(256)
void k_transpose(const float* __restrict__ fmap, int HW, int tiles_per_b,
                 unsigned short* __restrict__ fmT) {
  __shared__ unsigned short Ls[64][66];
  int b = blockIdx.x / tiles_per_b;
  int p0 = (blockIdx.x % tiles_per_b) * 64;
  int tid = threadIdx.x;
  for (int idx = tid; idx < 4096; idx += 256) {
    int c = idx >> 6, pos = idx & 63;
    Ls[c][pos] = f2bf(fmap[((size_t)b * 64 + c) * HW + p0 + pos]);
  }
  __syncthreads();
  for (int idx = tid; idx < 4096; idx += 256) {
    int pos = idx >> 6, c = idx & 63;
    fmT[((size_t)b * HW + p0 + pos) * 64 + c] = Ls[c][pos];
  }
}

// ---------------------------------------------------------------------------
// Repack weights to bf16 MFMA-A layouts (unchanged from round 6/7).
// ---------------------------------------------------------------------------
__global__ __launch_bounds__(256)
void k_repack(const float* __restrict__ cw,
              const float* __restrict__ c0, const float* __restrict__ c1,
              const float* __restrict__ c2, const float* __restrict__ fcw,
              const float* __restrict__ clsW, const float* __restrict__ regW,
              const float* __restrict__ chw, const float* __restrict__ rhw,
              unsigned short* __restrict__ Wr, unsigned short* __restrict__ Wc,
              unsigned short* __restrict__ fw, unsigned short* __restrict__ wm) {
  int idx = blockIdx.x * 256 + threadIdx.x;
  if (idx < 82944) {
    int c = idx & 63; int t = idx >> 6; int o = t % 48; t /= 48;
    int k = t % 9; int s = t / 9;
    Wr[idx] = f2bf(cw[((size_t)(s * 48 + o) * 64 + c) * 9 + k]);
  } else if (idx < 82944 + 165888) {
    int r = idx - 82944;
    int st, base, NC;
    if (r < 27648)            { st = 0; base = 0;     NC = 1; }
    else if (r < 82944)       { st = 1; base = 27648; NC = 2; }
    else                      { st = 2; base = 82944; NC = 3; }
    int r2 = r - base;
    int slice_id = r2 >> 10;
    int m = (r2 >> 9) & 1;
    int lane = (r2 >> 3) & 63;
    int j = r2 & 7;
    int i = slice_id / 27;
    int rem = slice_id % 27;
    int t = rem / 3;
    int s = rem % 3;
    int o = m * 32 + (lane & 31);
    int c = s * 16 + (lane >> 5) * 8 + j;
    const float* src = (st == 0) ? c0 : (st == 1) ? c1 : c2;
    Wc[r] = f2bf(src[((size_t)o * (NC * 48) + i * 48 + c) * 9 + t]);
  } else if (idx < 82944 + 165888 + 147456) {
    int q = idx - (82944 + 165888);
    int h = q / 2304; int kp = q % 2304; int j = kp >> 6; int c = kp & 63;
    fw[q] = f2bf(fcw[(size_t)h * 2304 + c * 36 + j]);
  } else if (idx < 82944 + 165888 + 147456 + 22528) {
    int q = idx - (82944 + 165888 + 147456);
    unsigned short v;
    if (q < 4096)        v = f2bf(clsW[q]);
    else if (q < 8192)   v = f2bf(clsW[4096 + (q - 4096)]);
    else if (q < 12288)  v = f2bf(regW[q - 8192]);
    else if (q < 16384)  v = f2bf(regW[4096 + (q - 12288)]);
    else if (q < 17408) { int r = q - 16384; int o = r >> 6, c = r & 63;
                          v = (o < 2) ? f2bf(chw[o * 64 + c]) : (unsigned short)0; }
    else                { int r = q - 17408; int o = r >> 6, c = r & 63;
                          v = (o < 76) ? f2bf(rhw[o * 64 + c]) : (unsigned short)0; }
    wm[q] = v;
  }
}

// ---------------------------------------------------------------------------
// K2: key/value in MFMA-B layouts. Block = (b, 64-key tile); 256 blocks.
// ---------------------------------------------------------------------------
__global__ __launch_bounds__(256)
void k_kv(const unsigned short* __restrict__ fmT, int H, int W,
          const float* __restrict__ fkey_w, const float* __restrict__ fkey_scale,
          const float* __restrict__ fkey_shift,
          const float* __restrict__ fval_w, const float* __restrict__ fval_b,
          unsigned short* __restrict__ keyT, unsigned short* __restrict__ valB) {
  __shared__ float pix[64][68];
  __shared__ __align__(16) unsigned short kout[64][80];
  __shared__ __align__(16) unsigned short vout[64][80];
  int tid = threadIdx.x;
  int b = blockIdx.x >> 2;
  int k0 = (blockIdx.x & 3) * 64;

  {
    int key = tid >> 2, cq = tid & 3;
    int k = k0 + key;
    float v[16];
    if (k < 250) {
      int r = k / 25, c2 = k % 25;
      int iy = (r * H) / 10, ix = (c2 * W) / 25;
      const unsigned short* src = fmT + ((size_t)b * H * W + iy * W + ix) * 64 + cq * 16;
      us8 a = *(const us8*)src;
      us8 bb = *(const us8*)(src + 8);
#pragma unroll
      for (int e = 0; e < 8; ++e) { v[e] = bf2f(a[e]); v[8 + e] = bf2f(bb[e]); }
    } else {
#pragma unroll
      for (int e = 0; e < 16; ++e) v[e] = 0.f;
    }
#pragma unroll
    for (int e = 0; e < 16; ++e) pix[key][cq * 16 + e] = v[e];
  }
  __syncthreads();

  {
    int o = tid >> 2, kq = tid & 3;
    float ak[16], av[16];
#pragma unroll
    for (int kk = 0; kk < 16; ++kk) { ak[kk] = 0.f; av[kk] = 0.f; }
    for (int c = 0; c < 64; ++c) {
      float wk = fkey_w[o * 64 + c], wvv = fval_w[o * 64 + c];
#pragma unroll
      for (int kk = 0; kk < 16; ++kk) {
        float pv = pix[kq * 16 + kk][c];
        ak[kk] += pv * wk; av[kk] += pv * wvv;
      }
    }
    float sc_ = fkey_scale[o], sh = fkey_shift[o], vb_ = fval_b[o];
#pragma unroll
    for (int kk = 0; kk < 16; ++kk) {
      int k = kq * 16 + kk;
      float kf = ak[kk] * sc_ + sh; kf = kf > 0.f ? kf : 0.f;
      kout[k][o] = f2bf(kf);
      vout[o][k] = f2bf(av[kk] + vb_);
    }
  }
  __syncthreads();

  {
    int row = tid >> 2, oq = tid & 3;
    *(us8*)(keyT + ((size_t)b * 256 + k0 + row) * 64 + oq * 16)     = *(us8*)&kout[row][oq * 16];
    *(us8*)(keyT + ((size_t)b * 256 + k0 + row) * 64 + oq * 16 + 8) = *(us8*)&kout[row][oq * 16 + 8];
    *(us8*)(valB + ((size_t)b * 64 + row) * 256 + k0 + oq * 16)     = *(us8*)&vout[row][oq * 16];
    *(us8*)(valB + ((size_t)b * 64 + row) * 256 + k0 + oq * 16 + 8) = *(us8*)&vout[row][oq * 16 + 8];
  }
}

// ---------------------------------------------------------------------------
// K1a: fused gather + conv_s (MFMA 16x16x32), round-6 block layout (22 tiles)
// + explicit depth-1 A-prefetch over the 18 (k,kk)-steps.
// ---------------------------------------------------------------------------
template <int STAGE>
__global__ __launch_bounds__(256, 3)
void k_gatherconv(const unsigned short* __restrict__ fmT,
                  const float* __restrict__ priors_cur,
                  const unsigned short* __restrict__ Wr,
                  const float* __restrict__ cscale, const float* __restrict__ cshift,
                  unsigned short* __restrict__ cfg) {
  constexpr int H = (STAGE == 0) ? 64 : (STAGE == 1) ? 32 : 16;
  constexpr int W = (STAGE == 0) ? 80 : (STAGE == 1) ? 40 : 20;
  constexpr int HW = H * W;

  __shared__ float posx[8][36], posy[8][36];
  __shared__ __align__(16) unsigned short Xs[360][64];

  int tid = threadIdx.x;
  int r0 = blockIdx.x * 8;

  for (int idx = tid; idx < 288; idx += 256) {
    int q = idx / 36, j = idx % 36;
    int bp = r0 + q;
    int k = 35 - j;
    int sx = (int)(((float)k / 35.0f) * 71.0f);
    float px = priors_cur[(size_t)bp * 78 + 6 + sx];
    posx[q][j] = px * (float)(W - 1);
    float fy = 1.0f - (float)sx / 71.0f;
    posy[q][j] = fy * (float)(H - 1);
  }
  __syncthreads();

  for (int idx = tid; idx < 360 * 8; idx += 256) {
    int row = idx >> 3, ch8 = idx & 7;
    int p = row - 4;
    unsigned short pk[8] = {0, 0, 0, 0, 0, 0, 0, 0};
    if (p >= 0 && p < 352) {
      int q = p / 44, x = p % 44;
      if (x >= 4 && x < 40) {
        int j = x - 4;
        int b = (r0 + q) / PP;
        float fx = posx[q][j];
        float fy = posy[q][j];
        float x0 = floorf(fx), y0 = floorf(fy);
        float wx = fx - x0, wy = fy - y0;
        float xs2[2] = {x0, x0 + 1.f};
        float ys2[2] = {y0, y0 + 1.f};
        float wxs[2] = {1.f - wx, wx};
        float wys[2] = {1.f - wy, wy};
        float accf[8] = {0.f, 0.f, 0.f, 0.f, 0.f, 0.f, 0.f, 0.f};
#pragma unroll
        for (int ty = 0; ty < 2; ++ty)
#pragma unroll
          for (int tx = 0; tx < 2; ++tx) {
            float xf = xs2[tx], yf = ys2[ty];
            bool v = (xf >= 0.f) && (xf <= (float)(W - 1)) &&
                     (yf >= 0.f) && (yf <= (float)(H - 1));
            int xi = (int)fminf(fmaxf(xf, 0.f), (float)(W - 1));
            int yi = (int)fminf(fmaxf(yf, 0.f), (float)(H - 1));
            float wgt = v ? (wxs[tx] * wys[ty]) : 0.f;
            const us8 vv = *(const us8*)(fmT + ((size_t)b * HW + yi * W + xi) * 64 + ch8 * 8);
#pragma unroll
            for (int e = 0; e < 8; ++e) accf[e] += wgt * bf2f(vv[e]);
          }
#pragma unroll
        for (int e = 0; e < 8; ++e) pk[e] = f2bf(accf[e]);
      }
    }
    int pc = ch8 ^ (row & 7);
    *(us8*)&Xs[row][pc * 8] = *(us8*)pk;
  }
  __syncthreads();

  int wv = tid >> 6, lane = tid & 63, l15 = lane & 15, quad = lane >> 4;
  f32x4 acc[3][6];
#pragma unroll
  for (int m = 0; m < 3; ++m)
#pragma unroll
    for (int s = 0; s < 6; ++s) acc[m][s] = (f32x4)0.f;

  // depth-1 A-prefetch over 18 steps (k 0..8, kk 0..1)
  bf16x8 afc[3];
#pragma unroll
  for (int m = 0; m < 3; ++m)
    afc[m] = ld8(Wr + ((size_t)(0 * 48 + m * 16 + l15)) * 64 + 0 * 32 + quad * 8);

#pragma unroll
  for (int step = 0; step < 18; ++step) {
    int k = step >> 1, kk = step & 1;
    bf16x8 afn[3];
    if (step < 17) {
      int k2 = (step + 1) >> 1, kk2 = (step + 1) & 1;
#pragma unroll
      for (int m = 0; m < 3; ++m)
        afn[m] = ld8(Wr + ((size_t)(k2 * 48 + m * 16 + l15)) * 64 + kk2 * 32 + quad * 8);
    }
#pragma unroll
    for (int s = 0; s < 6; ++s) {
      int nt = wv + 4 * s;
      if (nt < 22) {
        int row = nt * 16 + l15 + k;
        int pc = (kk * 4 + quad) ^ (row & 7);
        bf16x8 bfr = ld8(&Xs[row][pc * 8]);
#pragma unroll
        for (int m = 0; m < 3; ++m)
          acc[m][s] = __builtin_amdgcn_mfma_f32_16x16x32_bf16(afc[m], bfr, acc[m][s], 0, 0, 0);
      }
    }
    if (step < 17) {
#pragma unroll
      for (int m = 0; m < 3; ++m) afc[m] = afn[m];
    }
  }

#pragma unroll
  for (int s = 0; s < 6; ++s) {
    int nt = wv + 4 * s;
    if (nt < 22) {
      int p = nt * 16 + l15;
      int q = p / 44, x = p % 44;
      if (x >= 4 && x < 40) {
        int bp = r0 + q;
#pragma unroll
        for (int m = 0; m < 3; ++m) {
          int o0 = m * 16 + quad * 4;
          unsigned short pk[4];
#pragma unroll
          for (int rg = 0; rg < 4; ++rg) {
            float v = acc[m][s][rg] * cscale[o0 + rg] + cshift[o0 + rg];
            pk[rg] = f2bf(v > 0.f ? v : 0.f);
          }
          *(uint2*)(cfg + ((size_t)bp * 36 + (x - 4)) * 48 + o0) = *(uint2*)pk;
        }
      }
    }
  }
}

// ---------------------------------------------------------------------------
// K1b: cat conv with 32x32x16 MFMA, round-6 block layout (11 n-tiles, zero
// tile padding) + explicit depth-1 prefetch of A-pair and B-triple across the
// 27 slices of each NC group.
// ---------------------------------------------------------------------------
template <int STAGE>
__global__ __launch_bounds__(256, 3)
void k_cat(const unsigned short* __restrict__ cfg_all,
           const unsigned short* __restrict__ Wc,
           const float* __restrict__ kscale, const float* __restrict__ kshift,
           unsigned short* __restrict__ catf) {
  constexpr int NC = STAGE + 1;
  __shared__ __align__(16) unsigned short cfs[360][64];
  int tid = threadIdx.x;
  int r0 = blockIdx.x * 8;
  int wv = tid >> 6, lane = tid & 63;
  int l31 = lane & 31, half = lane >> 5;

  int nt0 = wv * 3;
  int ntn = (wv < 3) ? 3 : 2;       // 11 n-tiles total

  f32x16 acc[2][3];
#pragma unroll
  for (int m = 0; m < 2; ++m)
#pragma unroll
    for (int n = 0; n < 3; ++n) acc[m][n] = (f32x16)0.f;

#pragma unroll
  for (int i = 0; i < NC; ++i) {
    __syncthreads();
    for (int idx = tid; idx < 2160; idx += 256) {
      int row = idx / 6, ch = idx % 6;
      int p = row - 4;
      us8 v = (us8)(unsigned short)0;
      if (p >= 0 && p < 352) {
        int q = p / 44, x = p % 44;
        if (x >= 4 && x < 40) {
          v = *(const us8*)(cfg_all + (size_t)i * (12288ull * 36 * 48) +
                            ((size_t)(r0 + q) * 36 + (x - 4)) * 48 + ch * 8);
        }
      }
      *(us8*)&cfs[row][((ch ^ (row & 7)) * 8)] = v;
    }
    __syncthreads();

    // prologue: slice 0 (t=0, s=0)
    bf16x8 a0c, a1c, bc[3];
    {
      int sid = i * 27;
      a0c = ld8(Wc + (size_t)(sid * 2 + 0) * 512 + lane * 8);
      a1c = ld8(Wc + (size_t)(sid * 2 + 1) * 512 + lane * 8);
#pragma unroll
      for (int n = 0; n < 3; ++n) {
        if (n < ntn) {
          int row = (nt0 + n) * 32 + l31;
          int q = half ^ (row & 7);
          bc[n] = ld8(&cfs[row][q * 8]);
        }
      }
    }

#pragma unroll
    for (int u = 0; u < 27; ++u) {
      bf16x8 a0n, a1n, bn[3];
      if (u < 26) {
        int u2 = u + 1, t2 = u2 / 3, s2 = u2 % 3;
        int sid2 = i * 27 + u2;
        a0n = ld8(Wc + (size_t)(sid2 * 2 + 0) * 512 + lane * 8);
        a1n = ld8(Wc + (size_t)(sid2 * 2 + 1) * 512 + lane * 8);
#pragma unroll
        for (int n = 0; n < 3; ++n) {
          if (n < ntn) {
            int row = (nt0 + n) * 32 + l31 + t2;
            int q = (s2 * 2 + half) ^ (row & 7);
            bn[n] = ld8(&cfs[row][q * 8]);
          }
        }
      }
#pragma unroll
      for (int n = 0; n < 3; ++n) {
        if (n < ntn) {
          acc[0][n] = __builtin_amdgcn_mfma_f32_32x32x16_bf16(a0c, bc[n], acc[0][n], 0, 0, 0);
          acc[1][n] = __builtin_amdgcn_mfma_f32_32x32x16_bf16(a1c, bc[n], acc[1][n], 0, 0, 0);
        }
      }
      if (u < 26) {
        a0c = a0n; a1c = a1n;
#pragma unroll
        for (int n = 0; n < 3; ++n) bc[n] = bn[n];
      }
    }
  }

#pragma unroll
  for (int n = 0; n < 3; ++n) {
    if (n < ntn) {
      int p = (nt0 + n) * 32 + l31;
      int q = p / 44, x = p % 44;
      if (x >= 4 && x < 40) {
        int bp = r0 + q;
        unsigned short* dst = catf + ((size_t)bp * 36 + (x - 4)) * 64;
#pragma unroll
        for (int m = 0; m < 2; ++m) {
#pragma unroll
          for (int r = 0; r < 4; ++r) {
            int o0 = m * 32 + r * 8 + half * 4;
            unsigned short pk[4];
#pragma unroll
            for (int g = 0; g < 4; ++g) {
              int o = o0 + g;
              float v = acc[m][n][r * 4 + g] * kscale[o] + kshift[o];
              pk[g] = f2bf(v > 0.f ? v : 0.f);
            }
            *(uint2*)(dst + o0) = *(uint2*)pk;
          }
        }
      }
    }
  }
}

// ---------------------------------------------------------------------------
// helper: one 16(M)x16(N)x64(K) GEMM tile.
// ---------------------------------------------------------------------------
__device__ inline f32x4 gemm_tile(const unsigned short* __restrict__ Wrow0,
                                  const unsigned short* Xl, int l15, int quad) {
  f32x4 a = (f32x4)0.f;
#pragma unroll
  for (int kk = 0; kk < 2; ++kk) {
    bf16x8 af = ld8(Wrow0 + (size_t)l15 * 64 + kk * 32 + quad * 8);
    bf16x8 bx = ld8(Xl + l15 * 64 + (((kk * 4 + quad) ^ (l15 & 7)) * 8));
    a = __builtin_amdgcn_mfma_f32_16x16x32_bf16(af, bx, a, 0, 0, 0);
  }
  return a;
}

// ---------------------------------------------------------------------------
// K3: FUSED fc-GEMM + LayerNorm + attention + MLP heads + tan epilogue.
// One wave per 16 rois; grid = 768.
// ---------------------------------------------------------------------------
__global__ __launch_bounds__(64)
void k_fc_att(const unsigned short* __restrict__ catf,
              const unsigned short* __restrict__ fw,
              const float* __restrict__ fc_b,
              const float* __restrict__ ln_g, const float* __restrict__ ln_b,
              const unsigned short* __restrict__ keyT,
              const unsigned short* __restrict__ valB,
              const float* __restrict__ fq_w, const float* __restrict__ fq_b,
              const float* __restrict__ attW_w, const float* __restrict__ attW_b,
              const unsigned short* __restrict__ wm,
              const float* __restrict__ cls_mlp_b, const float* __restrict__ reg_mlp_b,
              const float* __restrict__ cls_head_b, const float* __restrict__ reg_head_b,
              const float* __restrict__ priors_cur,
              float* __restrict__ priors_next,
              float* __restrict__ preds) {
  __shared__ __align__(16) unsigned char smem[2048 + 4608 + 8192];
  unsigned short* qx = (unsigned short*)smem;            // q / x union [16][64]
  unsigned char* Bb = smem + 2048;                       // rf / hA,hB union
  unsigned char* Cb = smem + 2048 + 4608;                // fcb / sim / rego union

  int lane = threadIdx.x;
  int l15 = lane & 15, quad = lane >> 4;
  int rb = blockIdx.x * 16;
  int b = rb / PP;
  int p_base = rb % PP;

  float* rf = (float*)Bb;                                // [16][68] f32
  unsigned short* hA = (unsigned short*)Bb;              // [16][64] bf16
  unsigned short* hB = (unsigned short*)(Bb + 2304);
  float* fcb = (float*)Cb;                               // [16][68] f32 (dies before sim)
  unsigned short* simw = (unsigned short*)Cb;            // [16][256] bf16
  unsigned short* rego = (unsigned short*)Cb;            // [16][80] bf16
  unsigned short* clso = (unsigned short*)(Cb + 2560);   // [16][2]

  // ---- phase 0: fc GEMM (M=64 hidden, N=16 rois, K=2304) ----
  {
    f32x4 acc[4];
#pragma unroll
    for (int m = 0; m < 4; ++m) acc[m] = (f32x4)0.f;
    for (int ks = 0; ks < 72; ++ks) {
      int j = ks >> 1, ch = (ks & 1) * 32;
      bf16x8 bfr = ld8(catf + ((size_t)(rb + l15) * 36 + j) * 64 + ch + quad * 8);
#pragma unroll
      for (int m = 0; m < 4; ++m) {
        bf16x8 af = ld8(fw + (size_t)(m * 16 + l15) * 2304 + ks * 32 + quad * 8);
        acc[m] = __builtin_amdgcn_mfma_f32_16x16x32_bf16(af, bfr, acc[m], 0, 0, 0);
      }
    }
#pragma unroll
    for (int m = 0; m < 4; ++m) {
      f32x4 v;
#pragma unroll
      for (int rg = 0; rg < 4; ++rg) v[rg] = acc[m][rg] + fc_b[m * 16 + quad * 4 + rg];
      *(f32x4*)&fcb[l15 * 68 + m * 16 + quad * 4] = v;
    }
  }

  // ---- phase 1: LayerNorm + relu -> rf (f32) + q (bf16, swizzled) ----
  for (int rr = 0; rr < 16; ++rr) {
    float y = fcb[rr * 68 + lane];
    float s = y;
#pragma unroll
    for (int off = 32; off > 0; off >>= 1) s += __shfl_xor(s, off, 64);
    float mu = s * (1.f / 64.f);
    float d = y - mu;
    float v2 = d * d;
#pragma unroll
    for (int off = 32; off > 0; off >>= 1) v2 += __shfl_xor(v2, off, 64);
    float var = v2 * (1.f / 64.f);
    float r = d / sqrtf(var + 1e-5f) * ln_g[lane] + ln_b[lane];
    r = r > 0.f ? r : 0.f;
    rf[rr * 68 + lane] = r;
    int p = p_base + rr;
    float q = r * fq_w[p] + fq_b[p];
    q = q > 0.f ? q : 0.f;
    qx[rr * 64 + (((lane >> 3) ^ (rr & 7)) * 8) + (lane & 7)] = f2bf(q);
  }

  // ---- phase 2: QK^T + in-register softmax ----
  f32x4 sc[16];
#pragma unroll
  for (int nt = 0; nt < 16; ++nt) sc[nt] = (f32x4)0.f;
  const unsigned short* kb = keyT + (size_t)b * 256 * 64;
#pragma unroll
  for (int kk = 0; kk < 2; ++kk) {
    bf16x8 af = ld8(&qx[l15 * 64 + (((kk * 4 + quad) ^ (l15 & 7)) * 8)]);
#pragma unroll
    for (int nt = 0; nt < 16; ++nt) {
      bf16x8 bf_ = ld8(kb + (size_t)(nt * 16 + l15) * 64 + kk * 32 + quad * 8);
      sc[nt] = __builtin_amdgcn_mfma_f32_16x16x32_bf16(af, bf_, sc[nt], 0, 0, 0);
    }
  }
  float mx[4] = {-1e30f, -1e30f, -1e30f, -1e30f};
#pragma unroll
  for (int nt = 0; nt < 16; ++nt)
#pragma unroll
    for (int rg = 0; rg < 4; ++rg) {
      float s = sc[nt][rg] * 0.125f;
      if (nt == 15 && l15 >= 10) s = -1e30f;
      sc[nt][rg] = s;
      mx[rg] = fmaxf(mx[rg], s);
    }
#pragma unroll
  for (int rg = 0; rg < 4; ++rg)
#pragma unroll
    for (int off = 1; off < 16; off <<= 1)
      mx[rg] = fmaxf(mx[rg], __shfl_xor(mx[rg], off, 64));
  float sm[4] = {0.f, 0.f, 0.f, 0.f};
#pragma unroll
  for (int nt = 0; nt < 16; ++nt)
#pragma unroll
    for (int rg = 0; rg < 4; ++rg) {
      float e = expf(sc[nt][rg] - mx[rg]);
      sc[nt][rg] = e;
      sm[rg] += e;
    }
#pragma unroll
  for (int rg = 0; rg < 4; ++rg)
#pragma unroll
    for (int off = 1; off < 16; off <<= 1)
      sm[rg] += __shfl_xor(sm[rg], off, 64);
  float rs[4];
#pragma unroll
  for (int rg = 0; rg < 4; ++rg) rs[rg] = 1.f / sm[rg];
#pragma unroll
  for (int nt = 0; nt < 16; ++nt)
#pragma unroll
    for (int rg = 0; rg < 4; ++rg) {
      int row = quad * 4 + rg, col = nt * 16 + l15;
      simw[row * 256 + (((col >> 3) ^ (row & 7)) * 8) + (col & 7)] = f2bf(sc[nt][rg] * rs[rg]);
    }

  // ---- phase 3: PV + residual + attW ----
  f32x4 cv[4];
#pragma unroll
  for (int nt = 0; nt < 4; ++nt) cv[nt] = (f32x4)0.f;
  const unsigned short* vb = valB + (size_t)b * 64 * 256;
#pragma unroll
  for (int ks = 0; ks < 8; ++ks) {
    bf16x8 af = ld8(&simw[l15 * 256 + (((ks * 4 + quad) ^ (l15 & 7)) * 8)]);
#pragma unroll
    for (int nt = 0; nt < 4; ++nt) {
      bf16x8 bf_ = ld8(vb + (size_t)(nt * 16 + l15) * 256 + ks * 32 + quad * 8);
      cv[nt] = __builtin_amdgcn_mfma_f32_16x16x32_bf16(af, bf_, cv[nt], 0, 0, 0);
    }
  }
#pragma unroll
  for (int rg = 0; rg < 4; ++rg) {
    int row = quad * 4 + rg;
    int p = p_base + row;
    float aw = attW_w[p], ab = attW_b[p];
#pragma unroll
    for (int nt = 0; nt < 4; ++nt) {
      int c = nt * 16 + l15;
      float xv = rf[row * 68 + c] + cv[nt][rg] * aw + ab;
      qx[row * 64 + (((c >> 3) ^ (row & 7)) * 8) + (c & 7)] = f2bf(xv);
    }
  }

  // ---- phase 4: MLP chains ----
  const unsigned short* xw = qx;
#pragma unroll
  for (int mt = 0; mt < 4; ++mt) {
    f32x4 a = gemm_tile(wm + 0 + mt * 1024, xw, l15, quad);
#pragma unroll
    for (int rg = 0; rg < 4; ++rg) {
      int o = mt * 16 + quad * 4 + rg;
      float v = a[rg] + cls_mlp_b[o]; v = v > 0.f ? v : 0.f;
      hA[l15 * 64 + (((o >> 3) ^ (l15 & 7)) * 8) + (o & 7)] = f2bf(v);
    }
  }
#pragma unroll
  for (int mt = 0; mt < 4; ++mt) {
    f32x4 a = gemm_tile(wm + 4096 + mt * 1024, hA, l15, quad);
#pragma unroll
    for (int rg = 0; rg < 4; ++rg) {
      int o = mt * 16 + quad * 4 + rg;
      float v = a[rg] + cls_mlp_b[64 + o]; v = v > 0.f ? v : 0.f;
      hB[l15 * 64 + (((o >> 3) ^ (l15 & 7)) * 8) + (o & 7)] = f2bf(v);
    }
  }
  {
    f32x4 a = gemm_tile(wm + 16384, hB, l15, quad);
#pragma unroll
    for (int rg = 0; rg < 4; ++rg) {
      int o = quad * 4 + rg;
      if (o < 2) clso[l15 * 2 + o] = f2bf(a[rg] + cls_head_b[o]);
    }
  }
#pragma unroll
  for (int mt = 0; mt < 4; ++mt) {
    f32x4 a = gemm_tile(wm + 8192 + mt * 1024, xw, l15, quad);
#pragma unroll
    for (int rg = 0; rg < 4; ++rg) {
      int o = mt * 16 + quad * 4 + rg;
      float v = a[rg] + reg_mlp_b[o]; v = v > 0.f ? v : 0.f;
      hA[l15 * 64 + (((o >> 3) ^ (l15 & 7)) * 8) + (o & 7)] = f2bf(v);
    }
  }
#pragma unroll
  for (int mt = 0; mt < 4; ++mt) {
    f32x4 a = gemm_tile(wm + 12288 + mt * 1024, hA, l15, quad);
#pragma unroll
    for (int rg = 0; rg < 4; ++rg) {
      int o = mt * 16 + quad * 4 + rg;
      float v = a[rg] + reg_mlp_b[64 + o]; v = v > 0.f ? v : 0.f;
      hB[l15 * 64 + (((o >> 3) ^ (l15 & 7)) * 8) + (o & 7)] = f2bf(v);
    }
  }
#pragma unroll
  for (int mt = 0; mt < 5; ++mt) {
    f32x4 a = gemm_tile(wm + 17408 + mt * 1024, hB, l15, quad);
#pragma unroll
    for (int rg = 0; rg < 4; ++rg) {
      int o = mt * 16 + quad * 4 + rg;
      if (o < 76) rego[l15 * 80 + o] = f2bf(a[rg] + reg_head_b[o]);
    }
  }

  // ---- phase 5: epilogue (4 lanes per roi) ----
  {
    int p_local = lane >> 2, g = lane & 3;
    int bp = rb + p_local;
    const float* pc = priors_cur + (size_t)bp * 78;
    float r0v = bf2f(rego[p_local * 80 + 0]);
    float r1v = bf2f(rego[p_local * 80 + 1]);
    float r2v = bf2f(rego[p_local * 80 + 2]);
    float r3v = bf2f(rego[p_local * 80 + 3]);
    float p0 = pc[2] + r0v;
    float p1 = pc[3] + r1v;
    float p2 = pc[4] + r2v;
    float* po = preds + (size_t)bp * 78;
    float* pn = priors_next ? priors_next + (size_t)bp * 78 : nullptr;
    if (g == 0) {
      float c0v = bf2f(clso[p_local * 2 + 0]);
      float c1v = bf2f(clso[p_local * 2 + 1]);
      po[0] = c0v; po[1] = c1v;
      po[2] = p0; po[3] = p1; po[4] = p2; po[5] = r3v;
      if (pn) { pn[0] = c0v; pn[1] = c1v; pn[2] = p0; pn[3] = p1; pn[4] = p2; pn[5] = r3v; }
    }
    float t = tanf(p2 * PI_F + 1e-5f);
    float inv_t = 512.f / t;
#pragma unroll 2
    for (int i = g * 18; i < g * 18 + 18; ++i) {
      float py = 1.0f - (float)i / 71.0f;
      float offs = (p1 * 639.0f + (1.0f - py - p0) * inv_t) * (1.0f / 639.0f);
      po[6 + i] = offs + bf2f(rego[p_local * 80 + 4 + i]);
      if (pn) pn[6 + i] = offs;
    }
  }
}

// ---------------------------------------------------------------------------
extern "C" void kernel_launch(void* const* d_in, const int* in_sizes, int n_in,
                              void* d_out, int out_size, void* d_ws, size_t ws_size,
                              hipStream_t stream) {
  (void)in_sizes; (void)n_in; (void)out_size; (void)ws_size;
  const float* feat[3] = {(const float*)d_in[0], (const float*)d_in[1], (const float*)d_in[2]};
  const float* priors      = (const float*)d_in[3];
  const float* convs_w     = (const float*)d_in[4];
  const float* convs_scale = (const float*)d_in[5];
  const float* convs_shift = (const float*)d_in[6];
  const float* cat_w[3]    = {(const float*)d_in[7], (const float*)d_in[8], (const float*)d_in[9]};
  const float* cat_scale   = (const float*)d_in[10];
  const float* cat_shift   = (const float*)d_in[11];
  const float* fkey_w      = (const float*)d_in[12];
  const float* fkey_scale  = (const float*)d_in[13];
  const float* fkey_shift  = (const float*)d_in[14];
  const float* fval_w      = (const float*)d_in[15];
  const float* fval_b      = (const float*)d_in[16];
  const float* fq_w        = (const float*)d_in[17];
  const float* fq_b        = (const float*)d_in[18];
  const float* attW_w      = (const float*)d_in[19];
  const float* attW_b      = (const float*)d_in[20];
  const float* fc_w        = (const float*)d_in[21];
  const float* fc_b        = (const float*)d_in[22];
  const float* ln_g        = (const float*)d_in[23];
  const float* ln_b        = (const float*)d_in[24];
  const float* cls_mlp_w   = (const float*)d_in[25];
  const float* cls_mlp_b   = (const float*)d_in[26];
  const float* reg_mlp_w   = (const float*)d_in[27];
  const float* reg_mlp_b   = (const float*)d_in[28];
  const float* cls_head_w  = (const float*)d_in[29];
  const float* cls_head_b  = (const float*)d_in[30];
  const float* reg_head_w  = (const float*)d_in[31];
  const float* reg_head_b  = (const float*)d_in[32];
  float* out = (float*)d_out;

  char* wp = (char*)d_ws;
  auto alloc = [&](size_t bytes) { char* r = wp; wp += (bytes + 255) & ~(size_t)255; return r; };

  float* priA   = (float*)alloc((size_t)BB * PP * 78 * 4);
  float* priB   = (float*)alloc((size_t)BB * PP * 78 * 4);
  unsigned short* keyT = (unsigned short*)alloc((size_t)BB * 256 * 64 * 2);
  unsigned short* valB = (unsigned short*)alloc((size_t)BB * 64 * 256 * 2);
  unsigned short* Wr   = (unsigned short*)alloc(82944ull * 2);
  unsigned short* Wc   = (unsigned short*)alloc(165888ull * 2);
  unsigned short* fw   = (unsigned short*)alloc(147456ull * 2);
  unsigned short* wm   = (unsigned short*)alloc(22528ull * 2);
  unsigned short* cfg  = (unsigned short*)alloc(3ull * 12288 * 36 * 48 * 2);
  unsigned short* catf = (unsigned short*)alloc(12288ull * 36 * 64 * 2);
  unsigned short* fmT  = (unsigned short*)alloc((size_t)BB * 64 * 80 * 64 * 2);

  const int HW[3][2] = {{64, 80}, {32, 40}, {16, 20}};
  const size_t wcoff[3] = {0, 27648, 82944};

  k_init_priors<<<dim3((BB * PP * 78 + 255) / 256), dim3(256), 0, stream>>>(priors, priA);
  k_repack<<<dim3((418816 + 255) / 256), dim3(256), 0, stream>>>(
      convs_w, cat_w[0], cat_w[1], cat_w[2], fc_w,
      cls_mlp_w, reg_mlp_w, cls_head_w, reg_head_w, Wr, Wc, fw, wm);

  float* pcur = priA;
  float* pnext = priB;
  for (int s = 0; s < 3; ++s) {
    int H = HW[s][0], W = HW[s][1];
    int hw = H * W;
    int tiles = hw / 64;
    k_transpose<<<dim3(BB * tiles), dim3(256), 0, stream>>>(feat[s], hw, tiles, fmT);

    k_kv<<<dim3(BB * 4), dim3(256), 0, stream>>>(
        fmT, H, W, fkey_w, fkey_scale, fkey_shift, fval_w, fval_b, keyT, valB);

    if (s == 0) {
      k_gatherconv<0><<<dim3(1536), dim3(256), 0, stream>>>(
          fmT, pcur, Wr + 0 * 27648, convs_scale + 0, convs_shift + 0,
          cfg + 0ull * 12288 * 36 * 48);
      k_cat<0><<<dim3(1536), dim3(256), 0, stream>>>(
          cfg, Wc + wcoff[0], cat_scale + 0, cat_shift + 0, catf);
    } else if (s == 1) {
      k_gatherconv<1><<<dim3(1536), dim3(256), 0, stream>>>(
          fmT, pcur, Wr + 1 * 27648, convs_scale + 48, convs_shift + 48,
          cfg + 1ull * 12288 * 36 * 48);
      k_cat<1><<<dim3(1536), dim3(256), 0, stream>>>(
          cfg, Wc + wcoff[1], cat_scale + 64, cat_shift + 64, catf);
    } else {
      k_gatherconv<2><<<dim3(1536), dim3(256), 0, stream>>>(
          fmT, pcur, Wr + 2 * 27648, convs_scale + 96, convs_shift + 96,
          cfg + 2ull * 12288 * 36 * 48);
      k_cat<2><<<dim3(1536), dim3(256), 0, stream>>>(
          cfg, Wc + wcoff[2], cat_scale + 128, cat_shift + 128, catf);
    }

    k_fc_att<<<dim3(768), dim3(64), 0, stream>>>(
        catf, fw, fc_b, ln_g, ln_b, keyT, valB, fq_w, fq_b, attW_w, attW_b, wm,
        cls_mlp_b, reg_mlp_b, cls_head_b, reg_head_b,
        pcur, (s < 2) ? pnext : (float*)nullptr,
        out + (size_t)s * BB * PP * 78);

    float* tmp = pcur; pcur = pnext; pnext = tmp;
  }
}